// Round 1
// baseline (1146.258 us; speedup 1.0000x reference)
//
#include <hip/hip_runtime.h>

// GKAT layer, restructured:
//   ret = elu( (S @ (C @ V_ext)) / (S @ rowsum(C) + eps') )
// where S = exp(scale*Q@K^T - M_i), M_i = ||Q_i|| * max_j ||K_j|| * scale
// (Cauchy-Schwarz upper bound on rowmax; exact max cancels in the ratio).
// V_ext = [V | ones | zeros] (160 cols) so rowsum(C) rides as column 128 of C@V_ext.

#define LOG2E 1.44269504088896340736f
#define SCALE 0.088388347648318447f   // 1/sqrt(128)

typedef __attribute__((ext_vector_type(8))) short bf16x8;   // 8 bf16 (4 VGPRs)
typedef __attribute__((ext_vector_type(4))) float f32x4;

static __device__ __forceinline__ unsigned short f2bf(float f) {
    unsigned u = __float_as_uint(f);
    u = (u + 0x7fffu + ((u >> 16) & 1u)) >> 16;   // RNE
    return (unsigned short)u;
}
static __device__ __forceinline__ float bf2f(unsigned short b) {
    return __uint_as_float(((unsigned)b) << 16);
}

// ---------------------------------------------------------------------------
// Kernel 1: [Q|K|V] = feat @ [Wq|Wk|Wv].  M=8192, N=384, K=256, bf16 MFMA.
// Q,K stored row-major bf16 [8192][128]; V stored transposed VbT[160][8192]
// with row 128 = ones (rowsum column), rows 129..159 = 0.
// ---------------------------------------------------------------------------
__global__ __launch_bounds__(256) void qkv_mfma(
    const float* __restrict__ feat, const float* __restrict__ Wq,
    const float* __restrict__ Wk, const float* __restrict__ Wv,
    unsigned short* __restrict__ Qb, unsigned short* __restrict__ Kb,
    unsigned short* __restrict__ VbT) {
    __shared__ unsigned short As[32][264];   // feat tile, +8 pad (16B-aligned stride)
    __shared__ unsigned short Bs[384][40];   // W^T tile (k-slice of 32), +8 pad
    const int tid = threadIdx.x;
    const int m0 = blockIdx.x * 32;
    const int lane = tid & 63, wv = tid >> 6;
    const int mh = wv & 1, nh = wv >> 1;
    const int ln15 = lane & 15, quad = lane >> 4;

    // stage A: feat[m0..m0+32) all 256 k, fp32 -> bf16
    for (int i = tid; i < 2048; i += 256) {
        int r = i >> 6, c = i & 63;
        const float4 f = *(const float4*)(feat + (size_t)(m0 + r) * 256 + c * 4);
        unsigned short* p = &As[r][c * 4];
        p[0] = f2bf(f.x); p[1] = f2bf(f.y); p[2] = f2bf(f.z); p[3] = f2bf(f.w);
    }
    f32x4 acc[12];
    for (int t = 0; t < 12; t++) acc[t] = f32x4{0.f, 0.f, 0.f, 0.f};
    const float* Ws[3] = {Wq, Wk, Wv};
    for (int ks = 0; ks < 8; ks++) {
        __syncthreads();   // Bs safe to overwrite (also covers As on first iter)
        // stage B: W[ks*32..+32)[0..384) transposed into Bs[n][k]
        for (int i = tid; i < 3072; i += 256) {
            int kk = i / 96, nc = i % 96;
            int n0 = nc * 4;
            const float* W = Ws[n0 >> 7];
            const float4 f = *(const float4*)(W + (size_t)(ks * 32 + kk) * 128 + (n0 & 127));
            Bs[n0 + 0][kk] = f2bf(f.x); Bs[n0 + 1][kk] = f2bf(f.y);
            Bs[n0 + 2][kk] = f2bf(f.z); Bs[n0 + 3][kk] = f2bf(f.w);
        }
        __syncthreads();
        bf16x8 af = *(const bf16x8*)&As[mh * 16 + ln15][ks * 32 + quad * 8];
        for (int t = 0; t < 12; t++) {
            bf16x8 bf = *(const bf16x8*)&Bs[nh * 192 + t * 16 + ln15][quad * 8];
            acc[t] = __builtin_amdgcn_mfma_f32_16x16x32_bf16(af, bf, acc[t], 0, 0, 0);
        }
    }
    // epilogue: C/D layout col=lane&15, row=quad*4+reg (m89/m91 verified)
    for (int t = 0; t < 12; t++) {
        int n = nh * 192 + t * 16 + ln15;
        int mbase = m0 + mh * 16 + quad * 4;
        for (int reg = 0; reg < 4; reg++) {
            unsigned short b = f2bf(acc[t][reg]);
            int m = mbase + reg;
            if (n < 128)      Qb[(size_t)m * 128 + n] = b;
            else if (n < 256) Kb[(size_t)m * 128 + (n - 128)] = b;
            else              VbT[(size_t)(n - 256) * 8192 + m] = b;
        }
    }
    // VbT rows 128..159 over this block's m-range: ones row + zero pad
    for (int i = tid; i < 1024; i += 256) {
        int rr = i >> 5, c = i & 31;
        VbT[(size_t)(128 + rr) * 8192 + m0 + c] = (rr == 0) ? (unsigned short)0x3F80 : (unsigned short)0;
    }
}

// ---------------------------------------------------------------------------
// Kernel 2: row norms of Q (per-row) and global max row-norm^2 of K.
// ---------------------------------------------------------------------------
__global__ __launch_bounds__(128) void norms_kernel(
    const unsigned short* __restrict__ Qb, const unsigned short* __restrict__ Kb,
    float* __restrict__ qn2, unsigned* __restrict__ knmax) {
    const int r = blockIdx.x, j = threadIdx.x;
    float q = bf2f(Qb[(size_t)r * 128 + j]);
    float k = bf2f(Kb[(size_t)r * 128 + j]);
    float sq = q * q, sk = k * k;
    for (int m = 1; m < 64; m <<= 1) {
        sq += __shfl_xor(sq, m, 64);
        sk += __shfl_xor(sk, m, 64);
    }
    __shared__ float s0[2], s1[2];
    if ((j & 63) == 0) { s0[j >> 6] = sq; s1[j >> 6] = sk; }
    __syncthreads();
    if (j == 0)  qn2[r] = s0[0] + s0[1];
    if (j == 64) atomicMax(knmax, __float_as_uint(s1[0] + s1[1]));  // positive floats: uint order == float order
}

// ---------------------------------------------------------------------------
// Kernel 3: CVbT = (C @ V_ext)^T.  M=8192 (C rows), N=160, K=8192.
// The only HBM-heavy kernel: reads counting_attn once (256 MB).
// ---------------------------------------------------------------------------
__global__ __launch_bounds__(256) void cv_kernel(
    const float* __restrict__ C, const unsigned short* __restrict__ VbT,
    unsigned short* __restrict__ CVbT) {
    __shared__ unsigned short As[32][40];    // C tile bf16, pad -> 2-way (free)
    __shared__ unsigned short Bs[160][40];   // V_ext^T k-slice
    const int tid = threadIdx.x;
    const int m0 = blockIdx.x * 32;
    const int lane = tid & 63, wv = tid >> 6;
    const int mh = wv & 1, nh = wv >> 1;
    const int ln15 = lane & 15, quad = lane >> 4;
    f32x4 acc[5];
    for (int t = 0; t < 5; t++) acc[t] = f32x4{0.f, 0.f, 0.f, 0.f};
    for (int kb = 0; kb < 8192; kb += 32) {
        {   // stage A: 32 rows x 32 k, fp32 -> bf16 (1 float4/thread)
            int r = tid >> 3, c4 = tid & 7;
            const float4 f = *(const float4*)(C + (size_t)(m0 + r) * 8192 + kb + c4 * 4);
            unsigned short* p = &As[r][c4 * 4];
            p[0] = f2bf(f.x); p[1] = f2bf(f.y); p[2] = f2bf(f.z); p[3] = f2bf(f.w);
        }
        // stage B: VbT[n][kb..kb+32)
        for (int i = tid; i < 640; i += 256) {
            int n = i >> 2, c = i & 3;
            *(bf16x8*)&Bs[n][c * 8] = *(const bf16x8*)(VbT + (size_t)n * 8192 + kb + c * 8);
        }
        __syncthreads();
        bf16x8 af = *(const bf16x8*)&As[mh * 16 + ln15][quad * 8];
        for (int t = 0; t < 5; t++) {
            bf16x8 bf = *(const bf16x8*)&Bs[nh * 80 + t * 16 + ln15][quad * 8];
            acc[t] = __builtin_amdgcn_mfma_f32_16x16x32_bf16(af, bf, acc[t], 0, 0, 0);
        }
        __syncthreads();
    }
    for (int t = 0; t < 5; t++) {
        int n = nh * 80 + t * 16 + ln15;
        int mb = m0 + mh * 16 + quad * 4;
        ushort4 w;
        w.x = f2bf(acc[t][0]); w.y = f2bf(acc[t][1]);
        w.z = f2bf(acc[t][2]); w.w = f2bf(acc[t][3]);
        *(ushort4*)(CVbT + (size_t)n * 8192 + mb) = w;   // 4 consecutive m -> 8B store
    }
}

// ---------------------------------------------------------------------------
// Kernel 4: per 32-row block: S = exp(scale*Q@K^T - M_i) tile-by-tile,
// O += S @ CVbT^T; epilogue divides by crs column (n=128) and applies ELU.
// ---------------------------------------------------------------------------
__global__ __launch_bounds__(256) void flash_kernel(
    const unsigned short* __restrict__ Qb, const unsigned short* __restrict__ Kb,
    const unsigned short* __restrict__ CVbT, const float* __restrict__ qn2,
    const unsigned* __restrict__ knmax, float* __restrict__ out) {
    __shared__ unsigned short Qs[32][136];
    __shared__ unsigned short Ks[64][136];
    __shared__ unsigned short Ps[32][72];    // P round-trip: C-layout -> A-layout
    __shared__ unsigned short Cs[160][72];
    __shared__ float Ms[32];
    __shared__ float Dn[32];
    const int tid = threadIdx.x;
    const int i0 = blockIdx.x * 32;
    const int lane = tid & 63, wv = tid >> 6;
    const int mh = wv & 1, sh = wv >> 1;   // sh = key-half (QK phase) / n-half (PV phase)
    const int ln15 = lane & 15, quad = lane >> 4;

    for (int i = tid; i < 512; i += 256) {   // stage Q once
        int r = i >> 4, c = i & 15;
        *(bf16x8*)&Qs[r][c * 8] = *(const bf16x8*)(Qb + (size_t)(i0 + r) * 128 + c * 8);
    }
    if (tid < 32) {
        float kn2 = __uint_as_float(*knmax);
        Ms[tid] = sqrtf(qn2[i0 + tid] * kn2) * SCALE;   // >= rowmax of logits (Cauchy-Schwarz)
    }
    f32x4 acc[5];
    for (int t = 0; t < 5; t++) acc[t] = f32x4{0.f, 0.f, 0.f, 0.f};

    for (int kb = 0; kb < 8192; kb += 64) {
        for (int i = tid; i < 1024; i += 256) {   // K tile: 64 keys x 128 d
            int r = i >> 4, c = i & 15;
            *(bf16x8*)&Ks[r][c * 8] = *(const bf16x8*)(Kb + (size_t)(kb + r) * 128 + c * 8);
        }
        for (int i = tid; i < 1280; i += 256) {   // CV tile: 160 n x 64 k
            int n = i >> 3, c = i & 7;
            *(bf16x8*)&Cs[n][c * 8] = *(const bf16x8*)(CVbT + (size_t)n * 8192 + kb + c * 8);
        }
        __syncthreads();
        // QK phase: wave (mh, sh) computes P[mh*16..+16)[sh*32..+32)
        f32x4 pacc[2] = {f32x4{0.f, 0.f, 0.f, 0.f}, f32x4{0.f, 0.f, 0.f, 0.f}};
        for (int kk = 0; kk < 4; kk++) {
            bf16x8 af = *(const bf16x8*)&Qs[mh * 16 + ln15][kk * 32 + quad * 8];
            for (int t2 = 0; t2 < 2; t2++) {
                bf16x8 bf = *(const bf16x8*)&Ks[sh * 32 + t2 * 16 + ln15][kk * 32 + quad * 8];
                pacc[t2] = __builtin_amdgcn_mfma_f32_16x16x32_bf16(af, bf, pacc[t2], 0, 0, 0);
            }
        }
        for (int t2 = 0; t2 < 2; t2++) {
            int key = sh * 32 + t2 * 16 + ln15;
            for (int reg = 0; reg < 4; reg++) {
                int row = mh * 16 + quad * 4 + reg;
                float p = __expf(pacc[t2][reg] * SCALE - Ms[row]);   // <= ~1.0, no overflow
                Ps[row][key] = f2bf(p);
            }
        }
        __syncthreads();
        // PV phase: wave (mh, sh) computes O[mh*16..+16)[sh*80..+80)
        for (int ksub = 0; ksub < 2; ksub++) {
            bf16x8 af = *(const bf16x8*)&Ps[mh * 16 + ln15][ksub * 32 + quad * 8];
            for (int t = 0; t < 5; t++) {
                bf16x8 bf = *(const bf16x8*)&Cs[sh * 80 + t * 16 + ln15][ksub * 32 + quad * 8];
                acc[t] = __builtin_amdgcn_mfma_f32_16x16x32_bf16(af, bf, acc[t], 0, 0, 0);
            }
        }
        __syncthreads();
    }
    // broadcast deno (column n=128 = sh1/t3/col0)
    if (sh == 1 && ln15 == 0) {
        for (int reg = 0; reg < 4; reg++)
            Dn[mh * 16 + quad * 4 + reg] = acc[3][reg];
    }
    __syncthreads();
    for (int t = 0; t < 5; t++) {
        int n = sh * 80 + t * 16 + ln15;
        if (n >= 128) continue;
        for (int reg = 0; reg < 4; reg++) {
            int row = mh * 16 + quad * 4 + reg;
            float r = acc[t][reg] / (Dn[row] + 1e-9f);
            out[(size_t)(i0 + row) * 128 + n] = (r > 0.f) ? r : expm1f(r);
        }
    }
}

// ---------------------------------------------------------------------------
extern "C" void kernel_launch(void* const* d_in, const int* in_sizes, int n_in,
                              void* d_out, int out_size, void* d_ws, size_t ws_size,
                              hipStream_t stream) {
    const float* feat = (const float*)d_in[0];
    // d_in[1] = bg (unused scalar)
    const float* C    = (const float*)d_in[2];
    const float* Wq   = (const float*)d_in[3];
    const float* Wk   = (const float*)d_in[4];
    const float* Wv   = (const float*)d_in[5];
    float* out = (float*)d_out;

    char* ws = (char*)d_ws;
    unsigned short* Qb   = (unsigned short*)(ws + 0);          // 8192*128*2 = 2 MB
    unsigned short* Kb   = (unsigned short*)(ws + 2097152);    // 2 MB
    unsigned short* VbT  = (unsigned short*)(ws + 4194304);    // 160*8192*2 = 2.5 MB
    unsigned short* CVbT = (unsigned short*)(ws + 6815744);    // 2.5 MB
    float*          qn2  = (float*)(ws + 9437184);             // 32 KB
    unsigned*       knmax= (unsigned*)(ws + 9469952);          // 4 B   (total ~9.03 MB)

    hipMemsetAsync(knmax, 0, 4, stream);   // ws is poisoned 0xAA; must zero before atomicMax
    qkv_mfma<<<256, 256, 0, stream>>>(feat, Wq, Wk, Wv, Qb, Kb, VbT);
    norms_kernel<<<8192, 128, 0, stream>>>(Qb, Kb, qn2, knmax);
    cv_kernel<<<256, 256, 0, stream>>>(C, VbT, CVbT);
    flash_kernel<<<256, 256, 0, stream>>>(Qb, Kb, CVbT, qn2, knmax, out);
}

// Round 2
// 659.459 us; speedup vs baseline: 1.7382x; 1.7382x over previous
//
#include <hip/hip_runtime.h>

// GKAT layer, restructured:
//   ret = elu( (S @ (C @ V_ext)) / (S @ rowsum(C) + eps) )
// where S = exp(scale*Q@K^T - M_i), M_i = ||Q_i|| * max_j ||K_j|| * scale
// (Cauchy-Schwarz upper bound on rowmax; exact rowmax cancels in the ratio).
// V_ext = [V | ones | pad] so rowsum(C) rides as column 128 of C@V_ext.
//
// R2: flash = 512thr/M=128/key-split-4 + reg-prefetch + atomics into fp32 partials;
//     cv    = dist-2 reg-prefetch, A direct-from-C staging, HBM-paced.

#define SCALE 0.088388347648318447f   // 1/sqrt(128)

typedef __attribute__((ext_vector_type(8))) short bf16x8;   // 8 bf16 (4 VGPRs)
typedef __attribute__((ext_vector_type(4))) float f32x4;

static __device__ __forceinline__ unsigned short f2bf(float f) {
    unsigned u = __float_as_uint(f);
    u = (u + 0x7fffu + ((u >> 16) & 1u)) >> 16;   // RNE
    return (unsigned short)u;
}
static __device__ __forceinline__ float bf2f(unsigned short b) {
    return __uint_as_float(((unsigned)b) << 16);
}
static __device__ __forceinline__ bf16x8 pack8(const float4& a, const float4& b) {
    bf16x8 v;
    v[0] = (short)f2bf(a.x); v[1] = (short)f2bf(a.y);
    v[2] = (short)f2bf(a.z); v[3] = (short)f2bf(a.w);
    v[4] = (short)f2bf(b.x); v[5] = (short)f2bf(b.y);
    v[6] = (short)f2bf(b.z); v[7] = (short)f2bf(b.w);
    return v;
}

// ---------------------------------------------------------------------------
// Kernel 1: [Q|K|V] = feat @ [Wq|Wk|Wv].  M=8192, N=384, K=256 (unchanged v1).
// ---------------------------------------------------------------------------
__global__ __launch_bounds__(256) void qkv_mfma(
    const float* __restrict__ feat, const float* __restrict__ Wq,
    const float* __restrict__ Wk, const float* __restrict__ Wv,
    unsigned short* __restrict__ Qb, unsigned short* __restrict__ Kb,
    unsigned short* __restrict__ VbT) {
    __shared__ unsigned short As[32][264];
    __shared__ unsigned short Bs[384][40];
    const int tid = threadIdx.x;
    const int m0 = blockIdx.x * 32;
    const int lane = tid & 63, wv = tid >> 6;
    const int mh = wv & 1, nh = wv >> 1;
    const int ln15 = lane & 15, quad = lane >> 4;

    for (int i = tid; i < 2048; i += 256) {
        int r = i >> 6, c = i & 63;
        const float4 f = *(const float4*)(feat + (size_t)(m0 + r) * 256 + c * 4);
        unsigned short* p = &As[r][c * 4];
        p[0] = f2bf(f.x); p[1] = f2bf(f.y); p[2] = f2bf(f.z); p[3] = f2bf(f.w);
    }
    f32x4 acc[12];
    for (int t = 0; t < 12; t++) acc[t] = f32x4{0.f, 0.f, 0.f, 0.f};
    const float* Ws[3] = {Wq, Wk, Wv};
    for (int ks = 0; ks < 8; ks++) {
        __syncthreads();
        for (int i = tid; i < 3072; i += 256) {
            int kk = i / 96, nc = i % 96;
            int n0 = nc * 4;
            const float* W = Ws[n0 >> 7];
            const float4 f = *(const float4*)(W + (size_t)(ks * 32 + kk) * 128 + (n0 & 127));
            Bs[n0 + 0][kk] = f2bf(f.x); Bs[n0 + 1][kk] = f2bf(f.y);
            Bs[n0 + 2][kk] = f2bf(f.z); Bs[n0 + 3][kk] = f2bf(f.w);
        }
        __syncthreads();
        bf16x8 af = *(const bf16x8*)&As[mh * 16 + ln15][ks * 32 + quad * 8];
        for (int t = 0; t < 12; t++) {
            bf16x8 bf = *(const bf16x8*)&Bs[nh * 192 + t * 16 + ln15][quad * 8];
            acc[t] = __builtin_amdgcn_mfma_f32_16x16x32_bf16(af, bf, acc[t], 0, 0, 0);
        }
    }
    for (int t = 0; t < 12; t++) {
        int n = nh * 192 + t * 16 + ln15;
        int mbase = m0 + mh * 16 + quad * 4;
        for (int reg = 0; reg < 4; reg++) {
            unsigned short b = f2bf(acc[t][reg]);
            int m = mbase + reg;
            if (n < 128)      Qb[(size_t)m * 128 + n] = b;
            else if (n < 256) Kb[(size_t)m * 128 + (n - 128)] = b;
            else              VbT[(size_t)(n - 256) * 8192 + m] = b;
        }
    }
    for (int i = tid; i < 1024; i += 256) {
        int rr = i >> 5, c = i & 31;
        VbT[(size_t)(128 + rr) * 8192 + m0 + c] = (rr == 0) ? (unsigned short)0x3F80 : (unsigned short)0;
    }
}

// ---------------------------------------------------------------------------
// Kernel 2: row norms of Q, global max row-norm^2 of K (unchanged v1).
// ---------------------------------------------------------------------------
__global__ __launch_bounds__(128) void norms_kernel(
    const unsigned short* __restrict__ Qb, const unsigned short* __restrict__ Kb,
    float* __restrict__ qn2, unsigned* __restrict__ knmax) {
    const int r = blockIdx.x, j = threadIdx.x;
    float q = bf2f(Qb[(size_t)r * 128 + j]);
    float k = bf2f(Kb[(size_t)r * 128 + j]);
    float sq = q * q, sk = k * k;
    for (int m = 1; m < 64; m <<= 1) {
        sq += __shfl_xor(sq, m, 64);
        sk += __shfl_xor(sk, m, 64);
    }
    __shared__ float s0[2], s1[2];
    if ((j & 63) == 0) { s0[j >> 6] = sq; s1[j >> 6] = sk; }
    __syncthreads();
    if (j == 0)  qn2[r] = s0[0] + s0[1];
    if (j == 64) atomicMax(knmax, __float_as_uint(s1[0] + s1[1]));
}

// ---------------------------------------------------------------------------
// Kernel 3 v2: CVbT = (C @ V_ext)^T.  M=8192, N=160, K=8192.
// A (C rows) staged fp32->bf16 with distance-2 register prefetch; B (VbT)
// staged bf16 dist-2.  256 thr, M=32/block, grid 256.  HBM-paced (~800cyc/chunk).
// ---------------------------------------------------------------------------
__global__ __launch_bounds__(256) void cv_kernel(
    const float* __restrict__ C, const unsigned short* __restrict__ VbT,
    unsigned short* __restrict__ CVbT) {
    __shared__ unsigned short As[32][72];
    __shared__ unsigned short Bs[160][72];
    const int tid = threadIdx.x;
    const int m0 = blockIdx.x * 32;
    const int lane = tid & 63, wv = tid >> 6;
    const int mh = wv & 1, nh = wv >> 1;
    const int ln15 = lane & 15, quad = lane >> 4;

    const int ar = tid >> 3, ac = tid & 7;   // A slot: row 0..31, 8-float col-pair
    const float* Abase = C + (size_t)(m0 + ar) * 8192 + ac * 8;

    float4 pa0[2], pa1[2];
    bf16x8 pb[2][5];
    #pragma unroll
    for (int d = 0; d < 2; d++) {
        const int kb = d * 64;
        pa0[d] = *(const float4*)(Abase + kb);
        pa1[d] = *(const float4*)(Abase + kb + 4);
        #pragma unroll
        for (int i = 0; i < 5; i++) {
            int s = tid + i * 256;
            pb[d][i] = *(const bf16x8*)(VbT + (size_t)(s >> 3) * 8192 + kb + (s & 7) * 8);
        }
    }

    f32x4 acc[5];
    #pragma unroll
    for (int t = 0; t < 5; t++) acc[t] = f32x4{0.f, 0.f, 0.f, 0.f};

    // manual 2x unroll keeps prefetch register sets statically indexed
    for (int c = 0; c < 128; c += 2) {
        #pragma unroll
        for (int d = 0; d < 2; d++) {
            __syncthreads();   // prev chunk's LDS reads done
            *(bf16x8*)&As[ar][ac * 8] = pack8(pa0[d], pa1[d]);
            #pragma unroll
            for (int i = 0; i < 5; i++) {
                int s = tid + i * 256;
                *(bf16x8*)&Bs[s >> 3][(s & 7) * 8] = pb[d][i];
            }
            if (c + d + 2 < 128) {   // prefetch chunk c+d+2 into set d
                const int kb = (c + d + 2) * 64;
                pa0[d] = *(const float4*)(Abase + kb);
                pa1[d] = *(const float4*)(Abase + kb + 4);
                #pragma unroll
                for (int i = 0; i < 5; i++) {
                    int s = tid + i * 256;
                    pb[d][i] = *(const bf16x8*)(VbT + (size_t)(s >> 3) * 8192 + kb + (s & 7) * 8);
                }
            }
            __syncthreads();   // staging visible
            #pragma unroll
            for (int k2 = 0; k2 < 2; k2++) {
                bf16x8 af = *(const bf16x8*)&As[mh * 16 + ln15][k2 * 32 + quad * 8];
                #pragma unroll
                for (int t = 0; t < 5; t++) {
                    bf16x8 bf = *(const bf16x8*)&Bs[nh * 80 + t * 16 + ln15][k2 * 32 + quad * 8];
                    acc[t] = __builtin_amdgcn_mfma_f32_16x16x32_bf16(af, bf, acc[t], 0, 0, 0);
                }
            }
        }
    }
    #pragma unroll
    for (int t = 0; t < 5; t++) {
        int n = nh * 80 + t * 16 + ln15;
        int mb = m0 + mh * 16 + quad * 4;
        ushort4 w;
        w.x = f2bf(acc[t][0]); w.y = f2bf(acc[t][1]);
        w.z = f2bf(acc[t][2]); w.w = f2bf(acc[t][3]);
        *(ushort4*)(CVbT + (size_t)n * 8192 + mb) = w;
    }
}

// ---------------------------------------------------------------------------
// Kernel 4 v2: 512 thr, M=128 q-rows/block, key-split 4 (grid 64x4=256).
// Per 64-key chunk: QK (16 MFMA/wave) -> exp -> Ps -> PV (20 MFMA/wave).
// Reg-prefetch staging; Ms in registers; Ps stride 68 (conflict-free writes).
// Partial O accumulated into fp32 Of32[8192][160] via atomicAdd.
// ---------------------------------------------------------------------------
__global__ __launch_bounds__(512) void flash_kernel(
    const unsigned short* __restrict__ Qb, const unsigned short* __restrict__ Kb,
    const unsigned short* __restrict__ CVbT, const float* __restrict__ qn2,
    const unsigned* __restrict__ knmax, float* __restrict__ Of32) {
    __shared__ unsigned short Qs[128][136];
    __shared__ unsigned short Ks[64][136];
    __shared__ unsigned short Cs[192][72];   // 192 rows: staging divisibility pad
    __shared__ unsigned short Ps[128][68];   // stride 68: conflict-free b16 writes
    const int tid = threadIdx.x;
    const int rg = blockIdx.x >> 2, sp = blockIdx.x & 3;
    const int i0 = rg * 128;
    const int k0 = sp * 2048;                // this block's key range
    const int lane = tid & 63, wv = tid >> 6;
    const int ln15 = lane & 15, quad = lane >> 4;
    const int p4 = wv & 3;    // m-pair: rows 32*p4 .. +32 (same in QK and PV)
    const int h2 = wv >> 2;   // QK: key-half; PV: n-half

    for (int i = tid; i < 2048; i += 512) {   // stage Q once (128x128)
        int r = i >> 4, cq = i & 15;
        *(bf16x8*)&Qs[r][cq * 8] = *(const bf16x8*)(Qb + (size_t)(i0 + r) * 128 + cq * 8);
    }
    const float kn2 = __uint_as_float(*knmax);
    float Msr[2][4];   // Cauchy-Schwarz row bounds, in registers (no LDS reads)
    #pragma unroll
    for (int mt = 0; mt < 2; mt++)
        #pragma unroll
        for (int reg = 0; reg < 4; reg++) {
            int row = p4 * 32 + mt * 16 + quad * 4 + reg;
            Msr[mt][reg] = sqrtf(qn2[i0 + row] * kn2) * SCALE;
        }

    bf16x8 pkK[2], pkC[3];
    {   // prefetch chunk 0
        const int kb = k0;
        #pragma unroll
        for (int i = 0; i < 2; i++) {
            int s = tid + i * 512;   // K slot: 64 rows x 16 col-groups
            pkK[i] = *(const bf16x8*)(Kb + (size_t)(kb + (s >> 4)) * 128 + (s & 15) * 8);
        }
        #pragma unroll
        for (int i = 0; i < 3; i++) {
            int s = tid + i * 512;   // CV slot: 192 rows x 8 col-groups
            pkC[i] = *(const bf16x8*)(CVbT + (size_t)(s >> 3) * 8192 + kb + (s & 7) * 8);
        }
    }

    f32x4 acc[2][5];
    #pragma unroll
    for (int mt = 0; mt < 2; mt++)
        #pragma unroll
        for (int t = 0; t < 5; t++) acc[mt][t] = f32x4{0.f, 0.f, 0.f, 0.f};

    for (int c = 0; c < 32; c++) {
        __syncthreads();   // prev chunk's Ks/Cs reads done
        #pragma unroll
        for (int i = 0; i < 2; i++) {
            int s = tid + i * 512;
            *(bf16x8*)&Ks[s >> 4][(s & 15) * 8] = pkK[i];
        }
        #pragma unroll
        for (int i = 0; i < 3; i++) {
            int s = tid + i * 512;
            *(bf16x8*)&Cs[s >> 3][(s & 7) * 8] = pkC[i];
        }
        if (c + 1 < 32) {   // prefetch next chunk (L2-resident, dist-1 suffices)
            const int kb = k0 + (c + 1) * 64;
            #pragma unroll
            for (int i = 0; i < 2; i++) {
                int s = tid + i * 512;
                pkK[i] = *(const bf16x8*)(Kb + (size_t)(kb + (s >> 4)) * 128 + (s & 15) * 8);
            }
            #pragma unroll
            for (int i = 0; i < 3; i++) {
                int s = tid + i * 512;
                pkC[i] = *(const bf16x8*)(CVbT + (size_t)(s >> 3) * 8192 + kb + (s & 7) * 8);
            }
        }
        __syncthreads();   // staging visible

        // QK: rows 32*p4..+32 x keys 32*h2..+32
        f32x4 pacc[2][2];
        #pragma unroll
        for (int mt = 0; mt < 2; mt++)
            #pragma unroll
            for (int kt = 0; kt < 2; kt++) pacc[mt][kt] = f32x4{0.f, 0.f, 0.f, 0.f};
        #pragma unroll
        for (int kk = 0; kk < 4; kk++) {
            bf16x8 aq0 = *(const bf16x8*)&Qs[p4 * 32 + ln15][kk * 32 + quad * 8];
            bf16x8 aq1 = *(const bf16x8*)&Qs[p4 * 32 + 16 + ln15][kk * 32 + quad * 8];
            #pragma unroll
            for (int kt = 0; kt < 2; kt++) {
                bf16x8 bk = *(const bf16x8*)&Ks[h2 * 32 + kt * 16 + ln15][kk * 32 + quad * 8];
                pacc[0][kt] = __builtin_amdgcn_mfma_f32_16x16x32_bf16(aq0, bk, pacc[0][kt], 0, 0, 0);
                pacc[1][kt] = __builtin_amdgcn_mfma_f32_16x16x32_bf16(aq1, bk, pacc[1][kt], 0, 0, 0);
            }
        }
        #pragma unroll
        for (int mt = 0; mt < 2; mt++)
            #pragma unroll
            for (int kt = 0; kt < 2; kt++)
                #pragma unroll
                for (int reg = 0; reg < 4; reg++) {
                    int row = p4 * 32 + mt * 16 + quad * 4 + reg;
                    int key = h2 * 32 + kt * 16 + ln15;
                    float p = __expf(pacc[mt][kt][reg] * SCALE - Msr[mt][reg]);
                    Ps[row][key] = f2bf(p);
                }
        __syncthreads();   // Ps visible

        // PV: rows 32*p4..+32 x n = 80*h2..+80
        #pragma unroll
        for (int ks = 0; ks < 2; ks++) {
            bf16x8 ap0 = *(const bf16x8*)&Ps[p4 * 32 + ln15][ks * 32 + quad * 8];
            bf16x8 ap1 = *(const bf16x8*)&Ps[p4 * 32 + 16 + ln15][ks * 32 + quad * 8];
            #pragma unroll
            for (int t = 0; t < 5; t++) {
                bf16x8 bc = *(const bf16x8*)&Cs[h2 * 80 + t * 16 + ln15][ks * 32 + quad * 8];
                acc[0][t] = __builtin_amdgcn_mfma_f32_16x16x32_bf16(ap0, bc, acc[0][t], 0, 0, 0);
                acc[1][t] = __builtin_amdgcn_mfma_f32_16x16x32_bf16(ap1, bc, acc[1][t], 0, 0, 0);
            }
        }
    }
    // epilogue: accumulate partials (4 key-splits) into fp32
    #pragma unroll
    for (int mt = 0; mt < 2; mt++)
        #pragma unroll
        for (int t = 0; t < 5; t++)
            #pragma unroll
            for (int reg = 0; reg < 4; reg++) {
                int row = i0 + p4 * 32 + mt * 16 + quad * 4 + reg;
                int n = h2 * 80 + t * 16 + ln15;
                atomicAdd(&Of32[(size_t)row * 160 + n], acc[mt][t][reg]);
            }
}

// ---------------------------------------------------------------------------
// Kernel 5: out = elu(O / (deno + 1e-9)), deno = column 128 of Of32.
// ---------------------------------------------------------------------------
__global__ __launch_bounds__(256) void finalize_kernel(
    const float* __restrict__ Of32, float* __restrict__ out) {
    int idx = blockIdx.x * 256 + threadIdx.x;
    int i = idx >> 7, n = idx & 127;
    float deno = Of32[(size_t)i * 160 + 128] + 1e-9f;
    float v = Of32[(size_t)i * 160 + n] / deno;
    out[idx] = (v > 0.f) ? v : expm1f(v);
}

// ---------------------------------------------------------------------------
extern "C" void kernel_launch(void* const* d_in, const int* in_sizes, int n_in,
                              void* d_out, int out_size, void* d_ws, size_t ws_size,
                              hipStream_t stream) {
    const float* feat = (const float*)d_in[0];
    // d_in[1] = bg (unused scalar)
    const float* C    = (const float*)d_in[2];
    const float* Wq   = (const float*)d_in[3];
    const float* Wk   = (const float*)d_in[4];
    const float* Wv   = (const float*)d_in[5];
    float* out = (float*)d_out;

    char* ws = (char*)d_ws;
    unsigned short* Qb   = (unsigned short*)(ws + 0);          // 2 MB
    unsigned short* Kb   = (unsigned short*)(ws + 2097152);    // 2 MB
    unsigned short* VbT  = (unsigned short*)(ws + 4194304);    // 160x8192x2 = 2.5 MB
    unsigned short* CVbT = (unsigned short*)(ws + 6815744);    // 192x8192x2 = 3 MB (rows 160-191 pad)
    float*          Of32 = (float*)(ws + 9961472);             // 8192x160x4 = 5.25 MB
    float*          qn2  = (float*)(ws + 15204352);            // 32 KB
    unsigned*       knmax= (unsigned*)(ws + 15237120);         // 4 B   (total ~14.6 MB)

    hipMemsetAsync(knmax, 0, 4, stream);
    hipMemsetAsync(Of32, 0, 8192 * 160 * sizeof(float), stream);
    qkv_mfma<<<256, 256, 0, stream>>>(feat, Wq, Wk, Wv, Qb, Kb, VbT);
    norms_kernel<<<8192, 128, 0, stream>>>(Qb, Kb, qn2, knmax);
    cv_kernel<<<256, 256, 0, stream>>>(C, VbT, CVbT);
    flash_kernel<<<256, 512, 0, stream>>>(Qb, Kb, CVbT, qn2, knmax, Of32);
    finalize_kernel<<<4096, 256, 0, stream>>>(Of32, out);
}